// Round 8
// baseline (260.033 us; speedup 1.0000x reference)
//
#include <hip/hip_runtime.h>
#include <stdint.h>

#define LSEQ 2048
#define M_TOT 32768          // B*L
#define KDIM 2048            // 2H
#define NKT 64               // K tiles of 32
#define NCT 4                // col tiles of 256
#define NEG_INF_F (-10000000000.0f)

typedef _Float16 f16;
typedef f16 f16x4 __attribute__((ext_vector_type(4)));
typedef f16 f16x8 __attribute__((ext_vector_type(8)));
typedef float f32x4 __attribute__((ext_vector_type(4)));

// ---------------- ws layout ----------------
// [0, 64K)        sdec f32[16][1024]
// [64K, 576K)     part f32[4][32768]
// [2M, 6M)        we16 plain fp16 [1024][2048]
// [6M, ...)       encT tiled/swizzled fp16 A [rtl][64 kt][16KB] (chunked)
#define WS_SDEC_OFF  0
#define WS_PART_OFF  (64u << 10)
#define WS_WE16_OFF  (2u << 20)
#define WS_ENCT_OFF  (6u << 20)

__device__ inline void gload16(const void* g, void* l) {
    __builtin_amdgcn_global_load_lds(
        (const __attribute__((address_space(1))) void*)g,
        (__attribute__((address_space(3))) void*)l, 16, 0, 0);
}

// fast tanh(x)*s with sign fold
__device__ inline float tanh_mul(float x, float s) {
    float ax = __builtin_fabsf(x);
    float e  = __expf(-2.f * ax);
    float th = (1.f - e) * __builtin_amdgcn_rcpf(1.f + e);
    float sv = __uint_as_float(__float_as_uint(s) ^ (__float_as_uint(x) & 0x80000000u));
    return th * sv;
}

// W_e = attn_w[:, H:3H] -> plain fp16 [h][e]
__global__ void wecvt_kernel(const float* __restrict__ attn_w, f16* __restrict__ we16) {
    int idx = blockIdx.x * 256 + threadIdx.x;
    int h  = idx >> 9;
    int e4 = idx & 511;
    const float4 v4 = *reinterpret_cast<const float4*>(attn_w + (size_t)h * 3072 + 1024 + e4 * 4);
    f16x4 hv = { (f16)v4.x, (f16)v4.y, (f16)v4.z, (f16)v4.w };
    *reinterpret_cast<f16x4*>(we16 + (size_t)h * 2048 + e4 * 4) = hv;
}

// encoder_out -> tiled/swizzled fp16 A (measured-0-conflict swizzle):
// granule g: rtl=g>>16, kt=(g>>10)&63, p=g&1023, row=p>>2, sl=(p&3)^((row>>1)&3)
__global__ __launch_bounds__(256) void enccvt(const float* __restrict__ enc,
                                              f16* __restrict__ encT, int rt0) {
    int g = blockIdx.x * 2048 + threadIdx.x;
    #pragma unroll
    for (int q = 0; q < 8; ++q, g += 256) {
        int rtl = g >> 16;
        int rem = g & 65535;
        int kt  = rem >> 10;
        int p   = rem & 1023;
        int row = p >> 2;
        int sl  = (p & 3) ^ ((row >> 1) & 3);
        const float* s = enc + (size_t)((rt0 + rtl) * 256 + row) * 2048 + kt * 32 + sl * 8;
        float4 a = *(const float4*)s;
        float4 b = *(const float4*)(s + 4);
        f16x8 h = { (f16)a.x,(f16)a.y,(f16)a.z,(f16)a.w,(f16)b.x,(f16)b.y,(f16)b.z,(f16)b.w };
        *(f16x8*)(encT + (size_t)g * 8) = h;
    }
}

// score_dec[b][h] = attn_b[h] + sum_k v[b][k] * attn_w[h][k]
__global__ void sdec_kernel(const float* __restrict__ v,
                            const float* __restrict__ attn_w,
                            const float* __restrict__ attn_b,
                            float* __restrict__ sdec) {
    int gid  = blockIdx.x * 4 + (threadIdx.x >> 6);
    int lane = threadIdx.x & 63;
    int b = gid >> 10;
    int h = gid & 1023;
    const float* vr = v + b * 1024;
    const float* wr = attn_w + (size_t)h * 3072;
    float s = 0.f;
    #pragma unroll 4
    for (int k = lane; k < 1024; k += 64) s += vr[k] * wr[k];
    #pragma unroll
    for (int m = 1; m < 64; m <<= 1) s += __shfl_xor(s, m);
    if (lane == 0) sdec[b * 1024 + h] = s + attn_b[h];
}

// GEMM: 256x256 tile, 8 waves (2M x 4N), BK=32, 1 block/CU.
// A: 4-buf LDS ring (gload_lds, staged 3 ahead) -> register frag DOUBLE-BUFFER:
//    ds_reads for tile t+1 issue before MFMA(t); lgkmcnt lands after the cluster.
// B: register dbuf direct from L2-resident we16 (no LDS).
// One s_barrier per K-tile; counted vmcnt(6), never drained until tail.
__global__ __launch_bounds__(512, 2) void fused_gemm(
        const f16* __restrict__ encT,   // [rtl][64 kt][16KB]
        const f16* __restrict__ we16,   // [1024][2048]
        const float* __restrict__ sdec, // [16][1024]
        const float* __restrict__ vw,   // [1024]
        float* __restrict__ part,       // [NCT][32768]
        int rt0, int nblocks)
{
    // chunked XCD remap (nblocks % 8 == 0)
    const int cpx = nblocks >> 3;
    const int logical = ((int)blockIdx.x & 7) * cpx + ((int)blockIdx.x >> 3);
    const int rtl = logical >> 2;
    const int ct  = logical & 3;

    const int tid = threadIdx.x;
    const int l15 = tid & 15;
    const int l4  = (tid >> 4) & 3;
    const int wv  = tid >> 6;        // 0..7
    const int wm  = wv >> 2;         // 0..1  (128 rows each)
    const int wn  = wv & 3;          // 0..3  (64 cols each)

    __shared__ char lds[4 * 16384];  // ring of 4 A K-tile bufs
    __shared__ float red[4][256];

    const char* aT = (const char*)encT + ((size_t)rtl << 20);
    const f16* bptr = we16 + (size_t)(ct * 256 + wn * 64 + l15) * KDIM + l4 * 8;

    // A frag read offset: row = wm*128 + i*16 + l15, phys slot = l4 ^ ((l15>>1)&3)
    const int swz  = (l4 ^ ((l15 >> 1) & 3)) << 4;
    const int aoff = (wm * 128 + l15) * 64 + swz;

    f32x4 acc[8][4] = {};
    f16x8 fa0[8], fa1[8], b0[4], b1[4];

    auto stageA = [&](int t) {
        const char* s = aT + ((size_t)t << 14) + tid * 16;
        char* d = lds + ((t & 3) << 14) + tid * 16;
        gload16(s, d);
        gload16(s + 8192, d + 8192);
    };
    auto loadB = [&](f16x8 (&b)[4], int t) {
        const f16* p = bptr + t * 32;
        #pragma unroll
        for (int j = 0; j < 4; ++j)
            b[j] = *(const f16x8*)(p + (size_t)j * 16 * KDIM);
    };
    auto readA = [&](f16x8 (&fa)[8], int t) {
        const char* base = lds + ((t & 3) << 14) + aoff;
        #pragma unroll
        for (int i = 0; i < 8; ++i)
            fa[i] = *(const f16x8*)(base + i * 1024);
    };
    auto mfma = [&](f16x8 (&fa)[8], f16x8 (&b)[4]) {
        __builtin_amdgcn_s_setprio(1);
        #pragma unroll
        for (int i = 0; i < 8; ++i)
            #pragma unroll
            for (int j = 0; j < 4; ++j)
                acc[i][j] = __builtin_amdgcn_mfma_f32_16x16x32_f16(fa[i], b[j], acc[i][j], 0, 0, 0);
        __builtin_amdgcn_s_setprio(0);
    };

    auto body = [&](int t, f16x8 (&fac)[8], f16x8 (&fan)[8],
                    f16x8 (&bc)[4], f16x8 (&bn)[4]) {
        if (t + 3 < NKT) stageA(t + 3);          // 2 gload_lds -> buf (t+3)&3
        if (t + 1 < NKT) loadB(bn, t + 1);       // 4 global f16x8 loads
        // FIFO: outstanding = gl(t+2)2, B(t)4, gl(t+3)2, B(t+1)4 = 12.
        // vmcnt(6) drains gl(t+2) [for next iter's readA] and B(t) [this MFMA].
        if (t < NKT - 3) { asm volatile("s_waitcnt vmcnt(6)" ::: "memory"); }
        else             { asm volatile("s_waitcnt vmcnt(0)" ::: "memory"); }
        __builtin_amdgcn_s_barrier();            // all waves: buf t+1 valid
        __builtin_amdgcn_sched_barrier(0);
        if (t + 1 < NKT) readA(fan, t + 1);      // 8 ds_read_b128, drain under MFMA
        __builtin_amdgcn_sched_barrier(0);
        mfma(fac, bc);                           // no lgkm dependency
        asm volatile("s_waitcnt lgkmcnt(0)" ::: "memory");
        __builtin_amdgcn_sched_barrier(0);
    };

    // ---- prologue ----
    stageA(0); stageA(1); stageA(2);
    loadB(b0, 0);
    asm volatile("s_waitcnt vmcnt(8)" ::: "memory");   // buf0 landed (own loads)
    __builtin_amdgcn_s_barrier();                      // all waves' buf0 landed
    __builtin_amdgcn_sched_barrier(0);
    readA(fa0, 0);
    asm volatile("s_waitcnt lgkmcnt(0)" ::: "memory");
    __builtin_amdgcn_sched_barrier(0);

    #pragma unroll 1
    for (int tt = 0; tt < NKT; tt += 2) {
        body(tt,     fa0, fa1, b0, b1);
        body(tt + 1, fa1, fa0, b1, b0);
    }

    // ---------------- epilogue ----------------
    // C/D frag: col = l15, row = l4*4 + r; global row = rowbase + wm*128 + i*16 + l4*4 + r
    const int rowbase = (rt0 + rtl) * 256;
    const int colbase = ct * 256;
    const int bidx = (rt0 + rtl) >> 3;

    float sd[4], vs[4];
    #pragma unroll
    for (int j = 0; j < 4; ++j) {
        const int col = colbase + wn * 64 + j * 16 + l15;
        sd[j] = sdec[bidx * 1024 + col];
        vs[j] = vw[col];
    }
    float psum[8][4] = {};
    #pragma unroll
    for (int i = 0; i < 8; ++i)
        #pragma unroll
        for (int j = 0; j < 4; ++j)
            #pragma unroll
            for (int r = 0; r < 4; ++r)
                psum[i][r] += tanh_mul(acc[i][j][r] + sd[j], vs[j]);

    #pragma unroll
    for (int i = 0; i < 8; ++i)
        #pragma unroll
        for (int r = 0; r < 4; ++r) {
            float s = psum[i][r];
            s += __shfl_xor(s, 1); s += __shfl_xor(s, 2);
            s += __shfl_xor(s, 4); s += __shfl_xor(s, 8);
            psum[i][r] = s;
        }

    __syncthreads();
    if (l15 == 0) {
        #pragma unroll
        for (int i = 0; i < 8; ++i)
            #pragma unroll
            for (int r = 0; r < 4; ++r)
                red[wn][wm * 128 + i * 16 + l4 * 4 + r] = psum[i][r];
    }
    __syncthreads();
    if (tid < 256)
        part[(size_t)ct * M_TOT + rowbase + tid] =
            red[0][tid] + red[1][tid] + red[2][tid] + red[3][tid];
}

// softmax over L per batch; mask==0 -> -1e10; sums the NCT partials.
__global__ __launch_bounds__(512) void softmax_kernel(
        const float* __restrict__ part, const int* __restrict__ mask,
        float* __restrict__ out) {
    int b = blockIdx.x;
    int tid = threadIdx.x;
    int lane = tid & 63, w = tid >> 6;
    __shared__ float sred[8];

    float vals[4];
    #pragma unroll
    for (int p = 0; p < 4; ++p) {
        int row = b * LSEQ + tid + p * 512;
        float val = 0.f;
        #pragma unroll
        for (int q = 0; q < NCT; ++q) val += part[(size_t)q * M_TOT + row];
        vals[p] = (mask[row] == 0) ? NEG_INF_F : val;
    }
    float mx = fmaxf(fmaxf(vals[0], vals[1]), fmaxf(vals[2], vals[3]));
    #pragma unroll
    for (int m = 1; m < 64; m <<= 1) mx = fmaxf(mx, __shfl_xor(mx, m));
    if (lane == 0) sred[w] = mx;
    __syncthreads();
    float gmax = sred[0];
    #pragma unroll
    for (int i = 1; i < 8; ++i) gmax = fmaxf(gmax, sred[i]);

    float es[4]; float ssum = 0.f;
    #pragma unroll
    for (int p = 0; p < 4; ++p) { es[p] = expf(vals[p] - gmax); ssum += es[p]; }
    #pragma unroll
    for (int m = 1; m < 64; m <<= 1) ssum += __shfl_xor(ssum, m);
    __syncthreads();
    if (lane == 0) sred[w] = ssum;
    __syncthreads();
    float gsum = 0.f;
    #pragma unroll
    for (int i = 0; i < 8; ++i) gsum += sred[i];
    float inv = 1.f / gsum;
    #pragma unroll
    for (int p = 0; p < 4; ++p)
        out[b * LSEQ + tid + p * 512] = es[p] * inv;
}

extern "C" void kernel_launch(void* const* d_in, const int* in_sizes, int n_in,
                              void* d_out, int out_size, void* d_ws, size_t ws_size,
                              hipStream_t stream) {
    const float* enc    = (const float*)d_in[0];
    const int*   mask   = (const int*)  d_in[1];
    const float* v      = (const float*)d_in[2];
    const float* attn_w = (const float*)d_in[3];
    const float* attn_b = (const float*)d_in[4];
    const float* v_w    = (const float*)d_in[5];
    float* out = (float*)d_out;

    char* ws = (char*)d_ws;
    float* sdec = (float*)(ws + WS_SDEC_OFF);
    float* part = (float*)(ws + WS_PART_OFF);
    f16*   we16 = (f16*)  (ws + WS_WE16_OFF);
    f16*   encT = (f16*)  (ws + WS_ENCT_OFF);

    hipLaunchKernelGGL(wecvt_kernel, dim3(2048), dim3(256), 0, stream, attn_w, we16);
    hipLaunchKernelGGL(sdec_kernel,  dim3(4096), dim3(256), 0, stream, v, attn_w, attn_b, sdec);

    // row-chunking: each row-tile (256 rows) needs 1 MB of encT; keep rts even
    size_t cap = (ws_size > WS_ENCT_OFF) ? (ws_size - WS_ENCT_OFF) : 0;
    int crt = (int)(cap >> 20);
    if (crt > 128) crt = 128;
    crt &= ~1;
    if (crt < 2) crt = 2;
    for (int rt0 = 0; rt0 < 128; rt0 += crt) {
        int rts = (128 - rt0 < crt) ? (128 - rt0) : crt;
        hipLaunchKernelGGL(enccvt,     dim3(rts * 32), dim3(256), 0, stream, enc, encT, rt0);
        hipLaunchKernelGGL(fused_gemm, dim3(rts * 4),  dim3(512), 0, stream,
                           encT, we16, sdec, v_w, part, rt0, rts * 4);
    }
    hipLaunchKernelGGL(softmax_kernel, dim3(16), dim3(512), 0, stream, part, mask, out);
}